// Round 4
// baseline (547.168 us; speedup 1.0000x reference)
//
#include <hip/hip_runtime.h>
#include <math.h>

#define EPS 1e-5f
#define SQRT3F 1.7320508075688772f

__device__ __forceinline__ float wsum64(float x) {
#pragma unroll
    for (int o = 32; o > 0; o >>= 1) x += __shfl_xor(x, o, 64);
    return x;
}
__device__ __forceinline__ float hsum32(float x) {
#pragma unroll
    for (int o = 16; o > 0; o >>= 1) x += __shfl_xor(x, o, 64);
    return x;
}
__device__ __forceinline__ float sigm(float x) { return 1.f / (1.f + __expf(-x)); }
__device__ __forceinline__ float siluf(float x) { return x * sigm(x); }

// ---------------------------------------------------------------------------
// Kernel 1 (fused): blocks [0, nb_pre) do per-node preprocessing;
// blocks [nb_pre, nb_pre+nb_hist) do the CSR degree histogram.
// ---------------------------------------------------------------------------
__global__ __launch_bounds__(256) void pre_and_hist(
    int N, int E, int nb_pre,
    const float* __restrict__ feats, const float* __restrict__ equ,
    const int* __restrict__ nbrs,
    const float* __restrict__ ln1_w, const float* __restrict__ ln1_b,
    const float* __restrict__ eqn1_w, const float* __restrict__ eqn1_b,
    const float* __restrict__ inv_fc_w, const float* __restrict__ inv_fc_b,
    const float* __restrict__ equ_fc_w, const float* __restrict__ Winv,
    float* __restrict__ feats_ln, float* __restrict__ equ_ln,
    float* __restrict__ equ1t, float* __restrict__ PsP, float* __restrict__ PtP,
    int* __restrict__ deg)
{
    if (blockIdx.x >= nb_pre) {
        int i = (blockIdx.x - nb_pre) * 256 + threadIdx.x;
        if (i < E) atomicAdd(&deg[nbrs[E + i]], 1);
        return;
    }

    __shared__ float fl_s[4][128];
    __shared__ float el_s[4][128];
    __shared__ float f1_s[4][32];
    const int w = threadIdx.x >> 6;
    const int lane = threadIdx.x & 63;
    const int n = blockIdx.x * 4 + w;
    const bool act = n < N;
    const int c = lane & 31;
    const int half = lane >> 5;

    float x0 = 0.f, x1 = 0.f;
    if (act) { x0 = feats[n * 128 + lane]; x1 = feats[n * 128 + 64 + lane]; }
    float s  = wsum64(x0 + x1);
    float sq = wsum64(x0 * x0 + x1 * x1);
    float mu = s * (1.f / 128.f);
    float var = sq * (1.f / 128.f) - mu * mu;
    float rs = rsqrtf(var + EPS);
    float y0 = (x0 - mu) * rs * ln1_w[lane] + ln1_b[lane];
    float y1 = (x1 - mu) * rs * ln1_w[64 + lane] + ln1_b[64 + lane];
    if (act) { feats_ln[n * 128 + lane] = y0; feats_ln[n * 128 + 64 + lane] = y1; }
    fl_s[w][lane] = y0; fl_s[w][64 + lane] = y1;

    float a = 0.f, b = 0.f;
    if (act) { a = equ[n * 128 + lane]; b = equ[n * 128 + 64 + lane]; }
    float a0 = (half == 0) ? a : 0.f;
    float m0 = wsum64(a0) * (1.f / 32.f);
    float f0 = a0 - m0;
    float n0 = wsum64((half == 0) ? f0 * f0 : 0.f) * (1.f / 32.f);
    float rs0 = rsqrtf(n0 + EPS);
    float sq1 = ((half == 1) ? a * a : 0.f) + b * b;
    float n1 = wsum64(sq1) * (1.f / 96.f);
    float rs1 = rsqrtf(n1 + EPS);
    float w1c = eqn1_w[32 + c];
    float ea = (half == 0) ? (f0 * rs0 * eqn1_w[c] + eqn1_b[c]) : (a * rs1 * w1c);
    float eb = b * rs1 * w1c;
    if (act) { equ_ln[n * 128 + lane] = ea; equ_ln[n * 128 + 64 + lane] = eb; }
    el_s[w][lane] = ea; el_s[w][64 + lane] = eb;

    __syncthreads();

    {
        float acc = 0.f;
#pragma unroll 8
        for (int k = 0; k < 64; k++) {
            int kk = half * 64 + k;
            acc += fl_s[w][kk] * inv_fc_w[kk * 32 + c];
        }
        acc += __shfl_xor(acc, 32);
        if (half == 0) f1_s[w][c] = acc + inv_fc_b[c];
    }
    if (act) {
        float acc = 0.f, acc2 = 0.f;
#pragma unroll 8
        for (int k = 0; k < 32; k++) {
            float wv = equ_fc_w[k * 32 + c];
            acc  += el_s[w][half * 32 + k] * wv;
            acc2 += el_s[w][(half + 2) * 32 + k] * wv;
        }
        equ1t[n * 128 + c * 4 + half]     = acc;
        equ1t[n * 128 + c * 4 + half + 2] = acc2;
    }
    __syncthreads();
    if (!act) return;

    {
        const int jj = c;
        float4 aPs = {0.f, 0.f, 0.f, 0.f};
        float4 aPt = {0.f, 0.f, 0.f, 0.f};
#pragma unroll 4
        for (int k = 0; k < 16; k++) {
            int kk = half * 16 + k;
            float x = f1_s[w][kk];
            float4 w4 = *(const float4*)&Winv[kk * 128 + jj * 4];
            float4 v4 = *(const float4*)&Winv[(32 + kk) * 128 + jj * 4];
            aPs.x += x * w4.x; aPs.y += x * w4.y; aPs.z += x * w4.z; aPs.w += x * w4.w;
            aPt.x += x * v4.x; aPt.y += x * v4.y; aPt.z += x * v4.z; aPt.w += x * v4.w;
        }
        aPs.x += __shfl_xor(aPs.x, 32); aPs.y += __shfl_xor(aPs.y, 32);
        aPs.z += __shfl_xor(aPs.z, 32); aPs.w += __shfl_xor(aPs.w, 32);
        aPt.x += __shfl_xor(aPt.x, 32); aPt.y += __shfl_xor(aPt.y, 32);
        aPt.z += __shfl_xor(aPt.z, 32); aPt.w += __shfl_xor(aPt.w, 32);
        if (half == 0) {
            const float* ps = (const float*)&aPs;
            const float* pt = (const float*)&aPt;
#pragma unroll
            for (int i = 0; i < 4; i++) {
                int m = jj * 4 + i;
                PsP[n * 128 + (m & 31) * 4 + (m >> 5)] = ps[i];
                PtP[n * 128 + (m & 31) * 4 + (m >> 5)] = pt[i];
            }
        }
    }
}

// ---------------------------------------------------------------------------
// CSR scan + scatter
// ---------------------------------------------------------------------------
__global__ __launch_bounds__(1024) void csr_scan(int N, const int* __restrict__ deg,
                                                 int* __restrict__ row_start,
                                                 int* __restrict__ cursor)
{
    __shared__ int part[1024];
    const int t = threadIdx.x;
    const int per = (N + 1023) / 1024;
    const int base = t * per;
    int s = 0;
    for (int i = 0; i < per; i++) { int idx = base + i; if (idx < N) s += deg[idx]; }
    part[t] = s;
    __syncthreads();
    for (int off = 1; off < 1024; off <<= 1) {
        int v = (t >= off) ? part[t - off] : 0;
        __syncthreads();
        part[t] += v;
        __syncthreads();
    }
    int run = (t > 0) ? part[t - 1] : 0;
    for (int i = 0; i < per; i++) {
        int idx = base + i;
        if (idx < N) { row_start[idx] = run; cursor[idx] = run; run += deg[idx]; }
    }
}

__global__ __launch_bounds__(256) void csr_scatter(int E, const int* __restrict__ nb,
                                                   int* __restrict__ cursor,
                                                   int* __restrict__ csr_src)
{
    int i = blockIdx.x * 256 + threadIdx.x;
    if (i < E) {
        int d = nb[E + i];
        int s = nb[i];
        int pos = atomicAdd(&cursor[d], 1);
        csr_src[pos] = s;
    }
}

// ---------------------------------------------------------------------------
// Kernel 2: per-DST aggregation v2. One WAVE per dst: the two 32-lane halves
// split the dst's edge list; each half processes 4 edges per iteration.
// Partial sums combined with __shfl_xor(…,32). Grid-stride over dst chunks.
// ---------------------------------------------------------------------------
__global__ __launch_bounds__(256) void edge_agg(
    int N,
    const int* __restrict__ row_start, const int* __restrict__ deg_arr,
    const int* __restrict__ csr_src,
    const float* __restrict__ points, const float* __restrict__ equ1t,
    const float* __restrict__ PsP, const float* __restrict__ PtP,
    const float* __restrict__ feats_ln, const float* __restrict__ equ_ln,
    const float* __restrict__ Wl0g, const float* __restrict__ bl0g,
    const float* __restrict__ We2g, const float* __restrict__ Winvg,
    const float* __restrict__ binvg,
    float* __restrict__ out_inv, float* __restrict__ out_equ)
{
    __shared__ float WeP[32 * 128];   // [k][c][j] = Winv[64+k][j*32+c]
    __shared__ float Wl0P[16 * 128];  // [g][c][i] = Wl0[g*4+i][c]
    __shared__ float We2P[8 * 128];   // [g][c][i] = We2[g*4+i][c]
    __shared__ float BinvP[128];      // [c][j] = binv[j*32+c]
    __shared__ float bl0s[32];
    __shared__ float scr[4][512];     // per-wave scratch; halves use 256 each

    for (int idx = threadIdx.x; idx < 4096; idx += 256) {
        int k = idx >> 7, r = idx & 127, cc = r >> 2, j = r & 3;
        WeP[idx] = Winvg[(64 + k) * 128 + j * 32 + cc];
    }
    for (int idx = threadIdx.x; idx < 2048; idx += 256) {
        int g = idx >> 7, r = idx & 127, cc = r >> 2, i = r & 3;
        Wl0P[idx] = Wl0g[(g * 4 + i) * 32 + cc];
    }
    for (int idx = threadIdx.x; idx < 1024; idx += 256) {
        int g = idx >> 7, r = idx & 127, cc = r >> 2, i = r & 3;
        We2P[idx] = We2g[(g * 4 + i) * 32 + cc];
    }
    if (threadIdx.x < 128) BinvP[threadIdx.x] = binvg[(threadIdx.x & 3) * 32 + (threadIdx.x >> 2)];
    if (threadIdx.x < 32) bl0s[threadIdx.x] = bl0g[threadIdx.x];
    __syncthreads();

    const int w = threadIdx.x >> 6;
    const int lane = threadIdx.x & 63;
    const int h = lane >> 5;
    const int c = lane & 31;
    float* sc = &scr[w][h * 256];

    const int nchunk = (N + 3) / 4;
    for (int chunk = blockIdx.x; chunk < nchunk; chunk += gridDim.x) {
        const int n = chunk * 4 + w;
        if (n >= N) continue;

        const int start = row_start[n];
        const int len = deg_arr[n];
        const int nh0 = (len + 1) >> 1;
        const int hstart = start + (h ? nh0 : 0);
        const int hlen = h ? (len - nh0) : nh0;

        float4 te4 = *(const float4*)&equ1t[n * 128 + c * 4];
        float4 pt4 = *(const float4*)&PtP[n * 128 + c * 4];
        const float pdx = points[n * 3 + 0];
        const float pdy = points[n * 3 + 1];
        const float pdz = points[n * 3 + 2];
        float4 base = *(const float4*)&BinvP[c * 4];
        base.x += pt4.x; base.y += pt4.y; base.z += pt4.z; base.w += pt4.w;

        float4 acc = {0.f, 0.f, 0.f, 0.f};
        float4 aer = {0.f, 0.f, 0.f, 0.f};
        int cnt = 0;

        for (int i = 0; i < hlen; i += 4) {
            const int v = hlen - i;   // valid edges this chunk (>=1)
            int s[4];
#pragma unroll
            for (int t = 0; t < 4; t++) {
                int ii = i + t; if (ii > hlen - 1) ii = hlen - 1;
                s[t] = csr_src[hstart + ii];
            }
            float4 p[4];
            float e[4];
#pragma unroll
            for (int t = 0; t < 4; t++) {
                float4 a4 = *(const float4*)&equ1t[s[t] * 128 + c * 4];
                p[t] = *(const float4*)&PsP[s[t] * 128 + c * 4];
                float dx = SQRT3F * (points[s[t] * 3 + 0] - pdx);
                float dy = SQRT3F * (points[s[t] * 3 + 1] - pdy);
                float dz = SQRT3F * (points[s[t] * 3 + 2] - pdz);
                sc[t * 64 + c]      = a4.x * te4.x + a4.y * te4.y + a4.z * te4.z + a4.w * te4.w;
                sc[t * 64 + 32 + c] = a4.x + a4.y * dx + a4.z * dy + a4.w * dz;
                if (t < v) { aer.y += a4.y; aer.z += a4.z; aer.w += a4.w; }
            }
            // el0 matvec for 4 edges
#pragma unroll
            for (int t = 0; t < 4; t++) e[t] = bl0s[c];
#pragma unroll
            for (int g = 0; g < 16; g++) {
                float4 w4 = *(const float4*)&Wl0P[g * 128 + c * 4];
#pragma unroll
                for (int t = 0; t < 4; t++) {
                    float4 d4 = *(const float4*)&sc[t * 64 + g * 4];
                    e[t] += d4.x * w4.x + d4.y * w4.y + d4.z * w4.z + d4.w * w4.w;
                }
            }
#pragma unroll
            for (int t = 0; t < 4; t++) {
                e[t] = siluf(e[t]);
                sc[t * 64 + c] = e[t];
                if (t < v) aer.x += e[t];
            }
            // We matvec for 4 edges
            float4 m[4];
#pragma unroll
            for (int t = 0; t < 4; t++) {
                m[t] = base;
                m[t].x += p[t].x; m[t].y += p[t].y; m[t].z += p[t].z; m[t].w += p[t].w;
            }
#pragma unroll
            for (int g = 0; g < 8; g++) {
                float4 x4[4];
#pragma unroll
                for (int t = 0; t < 4; t++) x4[t] = *(const float4*)&sc[t * 64 + g * 4];
#pragma unroll
                for (int u = 0; u < 4; u++) {
                    float4 w4 = *(const float4*)&WeP[(g * 4 + u) * 128 + c * 4];
#pragma unroll
                    for (int t = 0; t < 4; t++) {
                        float x = ((const float*)&x4[t])[u];
                        m[t].x += x * w4.x; m[t].y += x * w4.y;
                        m[t].z += x * w4.z; m[t].w += x * w4.w;
                    }
                }
            }
#pragma unroll
            for (int t = 0; t < 4; t++) {
                float4 mm;
                mm.x = siluf(m[t].x); mm.y = siluf(m[t].y);
                mm.z = siluf(m[t].z); mm.w = siluf(m[t].w);
                float mx = fmaxf(fmaxf(mm.x, mm.y), fmaxf(mm.z, mm.w));
                unsigned long long bal = __ballot(mx > 0.f);
                if (t < v) {
                    acc.x += mm.x; acc.y += mm.y; acc.z += mm.z; acc.w += mm.w;
                    cnt += ((unsigned int)(bal >> (h * 32)) != 0u);
                }
            }
        }

        // combine the two halves
        acc.x += __shfl_xor(acc.x, 32); acc.y += __shfl_xor(acc.y, 32);
        acc.z += __shfl_xor(acc.z, 32); acc.w += __shfl_xor(acc.w, 32);
        aer.x += __shfl_xor(aer.x, 32); aer.y += __shfl_xor(aer.y, 32);
        aer.z += __shfl_xor(aer.z, 32); aer.w += __shfl_xor(aer.w, 32);
        cnt += __shfl_xor(cnt, 32);

        const float inv_nbn = 1.f / (1.f + (float)cnt);
        if (h == 0) {
            out_inv[n * 128 + c]      = (acc.x + feats_ln[n * 128 + c])      * inv_nbn;
            out_inv[n * 128 + 32 + c] = (acc.y + feats_ln[n * 128 + 32 + c]) * inv_nbn;
            out_inv[n * 128 + 64 + c] = (acc.z + feats_ln[n * 128 + 64 + c]) * inv_nbn;
            out_inv[n * 128 + 96 + c] = (acc.w + feats_ln[n * 128 + 96 + c]) * inv_nbn;

            *(float4*)&scr[w][c * 4] = aer;
            float4 eo = {0.f, 0.f, 0.f, 0.f};
#pragma unroll
            for (int g = 0; g < 8; g++) {
                float4 w4 = *(const float4*)&We2P[g * 128 + c * 4];
                const float* wp = (const float*)&w4;
#pragma unroll
                for (int t = 0; t < 4; t++) {
                    float4 a4 = *(const float4*)&scr[w][(g * 4 + t) * 4];
                    float wv = wp[t];
                    eo.x += a4.x * wv; eo.y += a4.y * wv; eo.z += a4.z * wv; eo.w += a4.w * wv;
                }
            }
            out_equ[n * 128 + c]      = (eo.x + equ_ln[n * 128 + c])      * inv_nbn;
            out_equ[n * 128 + 32 + c] = (eo.y + equ_ln[n * 128 + 32 + c]) * inv_nbn;
            out_equ[n * 128 + 64 + c] = (eo.z + equ_ln[n * 128 + 64 + c]) * inv_nbn;
            out_equ[n * 128 + 96 + c] = (eo.w + equ_ln[n * 128 + 96 + c]) * inv_nbn;
        }
    }
}

// ---------------------------------------------------------------------------
// Kernel 3: node_post (unchanged from R3).
// ---------------------------------------------------------------------------
__global__ __launch_bounds__(256) void node_post(
    int N,
    const float* __restrict__ ffn_ln_w, const float* __restrict__ ffn_ln_b,
    const float* __restrict__ W1g, const float* __restrict__ b1g,
    const float* __restrict__ W2g, const float* __restrict__ b2g,
    const float* __restrict__ eqn2_w, const float* __restrict__ eqn2_b,
    const float* __restrict__ fe1, const float* __restrict__ gate_w,
    const float* __restrict__ fe2,
    float* __restrict__ io_inv, float* __restrict__ io_equ)
{
    __shared__ float ht[128 * 36];
    __shared__ float es[8][128];
    __shared__ float gs[8][128];
    __shared__ float fe1P[8 * 128];
    __shared__ float fe2P[8 * 128];
    __shared__ float gatePa[8 * 128];
    __shared__ float gatePb[8 * 128];

    for (int idx = threadIdx.x; idx < 1024; idx += 256) {
        int g = idx >> 7, r = idx & 127, cc = r >> 2, i = r & 3;
        fe1P[idx]   = fe1[(g * 4 + i) * 32 + cc];
        fe2P[idx]   = fe2[(g * 4 + i) * 32 + cc];
        gatePa[idx] = gate_w[(g * 4 + i) * 64 + cc];
        gatePb[idx] = gate_w[(g * 4 + i) * 64 + 32 + cc];
    }
    __syncthreads();

    const int grp = threadIdx.x >> 5;
    const int c = threadIdx.x & 31;

    for (int q = 0; q < 4; q++) {
        const int nd = grp * 4 + q;
        const int n = blockIdx.x * 32 + nd;
        if (n >= N) break;

        float eq0 = io_equ[n * 128 + c];
        float eq1 = io_equ[n * 128 + 32 + c];
        float eq2 = io_equ[n * 128 + 64 + c];
        float eq3 = io_equ[n * 128 + 96 + c];
        float m0 = hsum32(eq0) * (1.f / 32.f);
        float f0 = eq0 - m0;
        float n0 = hsum32(f0 * f0) * (1.f / 32.f);
        float rs0 = rsqrtf(n0 + EPS);
        float n1 = hsum32(eq1 * eq1 + eq2 * eq2 + eq3 * eq3) * (1.f / 96.f);
        float rs1 = rsqrtf(n1 + EPS);
        float w1c = eqn2_w[32 + c];
        float4 ev;
        ev.x = f0 * rs0 * eqn2_w[c] + eqn2_b[c];
        ev.y = eq1 * rs1 * w1c;
        ev.z = eq2 * rs1 * w1c;
        ev.w = eq3 * rs1 * w1c;
        *(float4*)&es[grp][c * 4] = ev;

        float4 g4 = {0.f, 0.f, 0.f, 0.f};
#pragma unroll
        for (int g = 0; g < 8; g++) {
            float4 w4 = *(const float4*)&fe1P[g * 128 + c * 4];
            const float* wp = (const float*)&w4;
#pragma unroll
            for (int t = 0; t < 4; t++) {
                float4 a4 = *(const float4*)&es[grp][(g * 4 + t) * 4];
                float wv = wp[t];
                g4.x += a4.x * wv; g4.y += a4.y * wv; g4.z += a4.z * wv; g4.w += a4.w * wv;
            }
        }
        *(float4*)&gs[grp][c * 4] = g4;

        float aftA = 0.f, aftB = 0.f;
#pragma unroll
        for (int g = 0; g < 8; g++) {
            float4 wa4 = *(const float4*)&gatePa[g * 128 + c * 4];
            float4 wb4 = *(const float4*)&gatePb[g * 128 + c * 4];
            const float* wap = (const float*)&wa4;
            const float* wbp = (const float*)&wb4;
#pragma unroll
            for (int t = 0; t < 4; t++) {
                float g0 = gs[grp][(g * 4 + t) * 4];
                aftA += g0 * wap[t];
                aftB += g0 * wbp[t];
            }
        }
        float mult = sigm(aftB);
        float4 G;
        G.x = siluf(aftA);
        G.y = g4.y * mult; G.z = g4.z * mult; G.w = g4.w * mult;
        *(float4*)&es[grp][c * 4] = G;

        float4 oo = {0.f, 0.f, 0.f, 0.f};
#pragma unroll
        for (int g = 0; g < 8; g++) {
            float4 w4 = *(const float4*)&fe2P[g * 128 + c * 4];
            const float* wp = (const float*)&w4;
#pragma unroll
            for (int t = 0; t < 4; t++) {
                float4 a4 = *(const float4*)&es[grp][(g * 4 + t) * 4];
                float wv = wp[t];
                oo.x += a4.x * wv; oo.y += a4.y * wv; oo.z += a4.z * wv; oo.w += a4.w * wv;
            }
        }
        io_equ[n * 128 + c]      = oo.x + eq0;
        io_equ[n * 128 + 32 + c] = oo.y + eq1;
        io_equ[n * 128 + 64 + c] = oo.z + eq2;
        io_equ[n * 128 + 96 + c] = oo.w + eq3;

        float ip0 = io_inv[n * 128 + c];
        float ip1 = io_inv[n * 128 + 32 + c];
        float ip2 = io_inv[n * 128 + 64 + c];
        float ip3 = io_inv[n * 128 + 96 + c];
        float sm = hsum32(ip0 + ip1 + ip2 + ip3) * (1.f / 128.f);
        float sv = hsum32(ip0 * ip0 + ip1 * ip1 + ip2 * ip2 + ip3 * ip3) * (1.f / 128.f) - sm * sm;
        float rsv = rsqrtf(sv + EPS);
        ht[c * 36 + nd]         = (ip0 - sm) * rsv * ffn_ln_w[c]      + ffn_ln_b[c];
        ht[(32 + c) * 36 + nd]  = (ip1 - sm) * rsv * ffn_ln_w[32 + c] + ffn_ln_b[32 + c];
        ht[(64 + c) * 36 + nd]  = (ip2 - sm) * rsv * ffn_ln_w[64 + c] + ffn_ln_b[64 + c];
        ht[(96 + c) * 36 + nd]  = (ip3 - sm) * rsv * ffn_ln_w[96 + c] + ffn_ln_b[96 + c];
    }

    const int wid = threadIdx.x >> 6;
    const int half = (threadIdx.x >> 5) & 1;
    const int ndbase = wid * 8;
    const int nbase = blockIdx.x * 32 + ndbase;

    float4 acc8[8];
#pragma unroll
    for (int j = 0; j < 8; j++) acc8[j] = make_float4(0.f, 0.f, 0.f, 0.f);
    for (int k = 0; k < 64; k++) {
        const int kk = half * 64 + k;
        float4 w4 = *(const float4*)&W1g[kk * 128 + c * 4];
        float4 xA = *(const float4*)&ht[kk * 36 + ndbase];
        float4 xB = *(const float4*)&ht[kk * 36 + ndbase + 4];
        const float* xa = (const float*)&xA;
        const float* xb = (const float*)&xB;
#pragma unroll
        for (int j = 0; j < 4; j++) {
            float v = xa[j];
            acc8[j].x += v * w4.x; acc8[j].y += v * w4.y; acc8[j].z += v * w4.z; acc8[j].w += v * w4.w;
            float u = xb[j];
            acc8[4 + j].x += u * w4.x; acc8[4 + j].y += u * w4.y; acc8[4 + j].z += u * w4.z; acc8[4 + j].w += u * w4.w;
        }
    }
#pragma unroll
    for (int j = 0; j < 8; j++) {
        acc8[j].x += __shfl_xor(acc8[j].x, 32); acc8[j].y += __shfl_xor(acc8[j].y, 32);
        acc8[j].z += __shfl_xor(acc8[j].z, 32); acc8[j].w += __shfl_xor(acc8[j].w, 32);
    }
    if (half == 0) {
        float4 b4 = *(const float4*)&b1g[c * 4];
#pragma unroll
        for (int j = 0; j < 8; j++) {
            ht[(4 * c + 0) * 36 + ndbase + j] = fmaxf(acc8[j].x + b4.x, 0.f);
            ht[(4 * c + 1) * 36 + ndbase + j] = fmaxf(acc8[j].y + b4.y, 0.f);
            ht[(4 * c + 2) * 36 + ndbase + j] = fmaxf(acc8[j].z + b4.z, 0.f);
            ht[(4 * c + 3) * 36 + ndbase + j] = fmaxf(acc8[j].w + b4.w, 0.f);
        }
    }
#pragma unroll
    for (int j = 0; j < 8; j++) acc8[j] = make_float4(0.f, 0.f, 0.f, 0.f);
    for (int k = 0; k < 64; k++) {
        const int kk = half * 64 + k;
        float4 w4 = *(const float4*)&W2g[kk * 128 + c * 4];
        float4 xA = *(const float4*)&ht[kk * 36 + ndbase];
        float4 xB = *(const float4*)&ht[kk * 36 + ndbase + 4];
        const float* xa = (const float*)&xA;
        const float* xb = (const float*)&xB;
#pragma unroll
        for (int j = 0; j < 4; j++) {
            float v = xa[j];
            acc8[j].x += v * w4.x; acc8[j].y += v * w4.y; acc8[j].z += v * w4.z; acc8[j].w += v * w4.w;
            float u = xb[j];
            acc8[4 + j].x += u * w4.x; acc8[4 + j].y += u * w4.y; acc8[4 + j].z += u * w4.z; acc8[4 + j].w += u * w4.w;
        }
    }
#pragma unroll
    for (int j = 0; j < 8; j++) {
        acc8[j].x += __shfl_xor(acc8[j].x, 32); acc8[j].y += __shfl_xor(acc8[j].y, 32);
        acc8[j].z += __shfl_xor(acc8[j].z, 32); acc8[j].w += __shfl_xor(acc8[j].w, 32);
    }
    if (half == 0) {
        float4 b4 = *(const float4*)&b2g[c * 4];
#pragma unroll
        for (int j = 0; j < 8; j++) {
            const int n = nbase + j;
            if (n < N) {
                float4 ipre = *(const float4*)&io_inv[n * 128 + c * 4];
                float4 o;
                o.x = acc8[j].x + b4.x + ipre.x;
                o.y = acc8[j].y + b4.y + ipre.y;
                o.z = acc8[j].z + b4.z + ipre.z;
                o.w = acc8[j].w + b4.w + ipre.w;
                *(float4*)&io_inv[n * 128 + c * 4] = o;
            }
        }
    }
}

// ---------------------------------------------------------------------------
extern "C" void kernel_launch(void* const* d_in, const int* in_sizes, int n_in,
                              void* d_out, int out_size, void* d_ws, size_t ws_size,
                              hipStream_t stream)
{
    const float* feats     = (const float*)d_in[0];
    const float* equ       = (const float*)d_in[1];
    const float* points    = (const float*)d_in[2];
    const int*   neighbors = (const int*)d_in[3];
    const float* ln1_w     = (const float*)d_in[4];
    const float* ln1_b     = (const float*)d_in[5];
    const float* eqn1_w    = (const float*)d_in[6];
    const float* eqn1_b    = (const float*)d_in[7];
    const float* inv_fc_w  = (const float*)d_in[8];
    const float* inv_fc_b  = (const float*)d_in[9];
    const float* equ_fc_w  = (const float*)d_in[10];
    const float* fc_l0_w   = (const float*)d_in[11];
    const float* fc_l0_b   = (const float*)d_in[12];
    const float* equ_fc_2_w= (const float*)d_in[13];
    const float* inv_fc_1_w= (const float*)d_in[14];
    const float* inv_fc_1_b= (const float*)d_in[15];
    const float* ffn_ln_w  = (const float*)d_in[16];
    const float* ffn_ln_b  = (const float*)d_in[17];
    const float* ffn_w1    = (const float*)d_in[18];
    const float* ffn_b1    = (const float*)d_in[19];
    const float* ffn_w2    = (const float*)d_in[20];
    const float* ffn_b2    = (const float*)d_in[21];
    const float* eqn2_w    = (const float*)d_in[22];
    const float* eqn2_b    = (const float*)d_in[23];
    const float* fe1_w     = (const float*)d_in[24];
    const float* gate_w    = (const float*)d_in[25];
    const float* fe2_w     = (const float*)d_in[26];

    const int N = in_sizes[0] / 128;
    const int E = in_sizes[3] / 2;

    float* ws = (float*)d_ws;
    float* feats_ln = ws;
    float* equ_ln   = feats_ln + (size_t)N * 128;
    float* equ1t    = equ_ln   + (size_t)N * 128;
    float* PsP      = equ1t    + (size_t)N * 128;
    float* PtP      = PsP      + (size_t)N * 128;
    int* deg        = (int*)(PtP + (size_t)N * 128);
    int* row_start  = deg + N;
    int* cursor     = row_start + N;
    int* csr_src    = cursor + N;

    hipMemsetAsync(deg, 0, (size_t)N * sizeof(int), stream);

    const int nb_pre = (N + 3) / 4;
    const int nb_hist = (E + 255) / 256;
    pre_and_hist<<<nb_pre + nb_hist, 256, 0, stream>>>(
        N, E, nb_pre, feats, equ, neighbors,
        ln1_w, ln1_b, eqn1_w, eqn1_b,
        inv_fc_w, inv_fc_b, equ_fc_w, inv_fc_1_w,
        feats_ln, equ_ln, equ1t, PsP, PtP, deg);

    csr_scan<<<1, 1024, 0, stream>>>(N, deg, row_start, cursor);
    csr_scatter<<<(E + 255) / 256, 256, 0, stream>>>(E, neighbors, cursor, csr_src);

    float* out_inv = (float*)d_out;
    float* out_equ = out_inv + (size_t)N * 128;

    edge_agg<<<1280, 256, 0, stream>>>(
        N, row_start, deg, csr_src,
        points, equ1t, PsP, PtP, feats_ln, equ_ln,
        fc_l0_w, fc_l0_b, equ_fc_2_w, inv_fc_1_w, inv_fc_1_b,
        out_inv, out_equ);

    node_post<<<(N + 31) / 32, 256, 0, stream>>>(
        N, ffn_ln_w, ffn_ln_b, ffn_w1, ffn_b1, ffn_w2, ffn_b2,
        eqn2_w, eqn2_b, fe1_w, gate_w, fe2_w,
        out_inv, out_equ);
}